// Round 12
// baseline (84.487 us; speedup 1.0000x reference)
//
#include <hip/hip_runtime.h>
#include <hip/hip_bf16.h>

typedef short bf16x8 __attribute__((ext_vector_type(8)));
typedef float f32x4 __attribute__((ext_vector_type(4)));
typedef unsigned short u16;
typedef unsigned int u32;

#define NTOK 5120
#define NSDF 4096

__device__ __forceinline__ float b2f(u16 x){
  u32 u = ((u32)x) << 16; float f; __builtin_memcpy(&f, &u, 4); return f;
}
__device__ __forceinline__ u16 f2b(float f){
  u32 u; __builtin_memcpy(&u, &f, 4);
  return (u16)((u + 0x7fffu + ((u >> 16) & 1u)) >> 16);
}
__device__ __forceinline__ u32 cvtpk(float lo, float hi){
  u32 r;
  asm("v_cvt_pk_bf16_f32 %0, %1, %2" : "=v"(r) : "v"(lo), "v"(hi));
  return r;
}
__device__ __forceinline__ f32x4 mfma16(bf16x8 a, bf16x8 b, f32x4 c){
  return __builtin_amdgcn_mfma_f32_16x16x32_bf16(a, b, c, 0, 0, 0);
}
__device__ __forceinline__ void gld16(const void* g, void* l){
  __builtin_amdgcn_global_load_lds(
      (const __attribute__((address_space(1))) u32*)g,
      (__attribute__((address_space(3))) u32*)l, 16, 0, 0);
}

// ---------------- Kp: convert/transpose all weights f32 -> bf16 into ws
__global__ __launch_bounds__(256) void k_prep(
    const float* __restrict__ WQ, const float* __restrict__ WK, const float* __restrict__ WV,
    const float* __restrict__ W_out, const float* __restrict__ W_emb,
    const float* __restrict__ W_c3, const float* __restrict__ Wc,
    u16* __restrict__ Wt, u16* __restrict__ Wto, u16* __restrict__ Wemb_b,
    u16* __restrict__ Wc3_b, u16* __restrict__ Wcb)
{
  int gid = blockIdx.x * 256 + threadIdx.x;
  int gsz = gridDim.x * 256;
  for (int i = gid; i < 49152; i += gsz){       // 3*8*64*32
    int m = i >> 14, r = i & 16383;
    int h = r >> 11, d = (r >> 5) & 63, e = r & 31;
    const float* src = (m == 0) ? WQ : ((m == 1) ? WK : WV);
    float v = src[(h * 64 + d) * 32 + e];
    if (m == 0) v *= 0.17677669529663689f * 1.4426950408889634f;  // 1/sqrt(32)*log2(e)
    Wt[((m * 8 + h) * 32 + e) * 64 + d] = f2b(v);
  }
  for (int i = gid; i < 16384; i += gsz){       // 256*64
    int k = i >> 6, d = i & 63;
    Wto[d * 256 + k] = f2b(W_out[i]);
  }
  for (int i = gid; i < 4096; i += gsz) Wemb_b[i] = f2b(W_emb[i]);
  for (int i = gid; i < 4096; i += gsz) Wc3_b[i] = f2b(W_c3[i]);
  for (int i = gid; i < 20480; i += gsz) Wcb[i] = f2b(Wc[i]);
}

// ---------------- K0: patch embed (sdf + frames) + pos_emb -> X (bf16 [5120][64])
__global__ __launch_bounds__(256) void k_build_x(
    const float* __restrict__ cond1, const float* __restrict__ cond2,
    const u16* __restrict__ Wemb_b, const float* __restrict__ b_emb,
    const u16* __restrict__ Wc3_b, const float* __restrict__ b_c3,
    const float* __restrict__ pos, u16* __restrict__ Xout)
{
  __shared__ __align__(16) u16 Psh[64][72];
  int b = blockIdx.x, t = threadIdx.x;
  bool sdb = (b < 64);
  {
    int nl = t >> 2, sub = t & 3;
    const float* src = sdb ? cond1 : cond2;
    int nn = sdb ? (b * 64 + nl) : (b * 64 + nl - NSDF);
    int g0 = nn >> 8, g1 = (nn >> 4) & 15, g2 = nn & 15;
    const float* sp = src + (g0 * 4 + sub) * 4096 + g1 * 4 * 64 + g2 * 4;
    for (int p1 = 0; p1 < 4; ++p1){
      float4 v = *(const float4*)(sp + p1 * 64);
      ushort4 o;
      o.x = f2b(v.x); o.y = f2b(v.y); o.z = f2b(v.z); o.w = f2b(v.w);
      *(ushort4*)&Psh[nl][sub * 16 + p1 * 4] = o;
    }
  }
  __syncthreads();
  int w = t >> 6, lane = t & 63, l15 = lane & 15, g = lane >> 4;
  const u16* Wm = sdb ? Wc3_b : Wemb_b;
  const float* bias = sdb ? b_c3 : b_emb;
  bf16x8 a0 = *(const bf16x8*)&Psh[w * 16 + l15][g * 8];
  bf16x8 a1 = *(const bf16x8*)&Psh[w * 16 + l15][32 + g * 8];
  for (int nb = 0; nb < 4; ++nb){
    bf16x8 b0 = *(const bf16x8*)(Wm + (nb * 16 + l15) * 64 + g * 8);
    bf16x8 b1 = *(const bf16x8*)(Wm + (nb * 16 + l15) * 64 + 32 + g * 8);
    f32x4 acc = {0.f, 0.f, 0.f, 0.f};
    acc = mfma16(a0, b0, acc);
    acc = mfma16(a1, b1, acc);
    int d = nb * 16 + l15;
    float bs = bias[d];
    for (int r = 0; r < 4; ++r){
      int tok = b * 64 + w * 16 + g * 4 + r;
      float v = acc[r] + bs + pos[tok * 64 + d];
      Xout[tok * 64 + d] = f2b(v);
    }
  }
}

// ---------------- K1: QKV projection, wave-per-(m,h)-pair. grid 480 = 80 x 6.
__global__ __launch_bounds__(256) void k_qkv(
    const u16* __restrict__ X, const u16* __restrict__ Wt,
    u16* __restrict__ Q, u16* __restrict__ K, u16* __restrict__ VT)
{
  __shared__ __align__(16) u16 Xsh[64][72];
  int bid = blockIdx.x, b = bid / 6, grp = bid % 6;
  int t = threadIdx.x;
  {
    int nl = t >> 2, cb = t & 3;
    const u16* sp = X + (b * 64 + nl) * 64 + cb * 16;
    *(bf16x8*)&Xsh[nl][cb * 16] = *(const bf16x8*)(sp);
    *(bf16x8*)&Xsh[nl][cb * 16 + 8] = *(const bf16x8*)(sp + 8);
  }
  __syncthreads();
  int w = t >> 6, lane = t & 63, l15 = lane & 15, g = lane >> 4;
  int pair = grp * 4 + w, m = pair >> 3, h = pair & 7;
  bf16x8 a0[4], a1[4];
  for (int ms = 0; ms < 4; ++ms){
    a0[ms] = *(const bf16x8*)&Xsh[ms * 16 + l15][g * 8];
    a1[ms] = *(const bf16x8*)&Xsh[ms * 16 + l15][32 + g * 8];
  }
  for (int nb = 0; nb < 2; ++nb){
    const u16* wp = Wt + ((m * 8 + h) * 32 + nb * 16 + l15) * 64;
    bf16x8 b0 = *(const bf16x8*)(wp + g * 8);
    bf16x8 b1 = *(const bf16x8*)(wp + 32 + g * 8);
    int e = nb * 16 + l15;
    for (int ms = 0; ms < 4; ++ms){
      f32x4 acc = {0.f, 0.f, 0.f, 0.f};
      acc = mfma16(a0[ms], b0, acc);
      acc = mfma16(a1[ms], b1, acc);
      for (int r = 0; r < 4; ++r){
        int n = b * 64 + ms * 16 + g * 4 + r;
        u16 v = f2b(acc[r]);
        if (m == 0)      Q[(h * NTOK + n) * 32 + e] = v;
        else if (m == 1) K[(h * NTOK + n) * 32 + e] = v;
        else             VT[(h * 32 + e) * NTOK + n] = v;
      }
    }
  }
}

// ---------------- K2: flash attention, counted-vmcnt pipeline + T5 setprio.
// split-K x4, XCD swizzle, 4 waves x 32q, 128-kv block-coop tiles, gld16 dbuf.
// Opb laid out [h][n][sp][e], lpart [h][n][sp] for coalesced merge reads.
__global__ __launch_bounds__(256) void k_attn(
    const u16* __restrict__ Q, const u16* __restrict__ K, const u16* __restrict__ VT,
    u16* __restrict__ Opb, float* __restrict__ lpart)
{
  __shared__ __align__(16) u16 Ksh[2][128 * 32];
  __shared__ __align__(16) u16 Vsh[2][32 * 128];
  int bid = blockIdx.x;
  int x = bid & 7;
  int inner = bid >> 3;
  int qb = inner % 40;
  int p = x + 8 * (inner / 40);
  int sp = p >> 3, h = p & 7;
  int t = threadIdx.x, w = t >> 6, lane = t & 63, l15 = lane & 15, g = lane >> 4;
  int q0w = qb * 128 + w * 32;
  int kb = sp * 1280;
  int wb = w * 512;

  int rho0 = t >> 2, cpK = t & 3;
  int key0 = (rho0 & 0x60) | ((rho0 & 0x0C) << 1) | ((rho0 & 0x10) >> 2) | (rho0 & 3);
  int clogK = cpK ^ (rho0 & 3);
  const uint4* kg0 = (const uint4*)(K + (size_t)(h * NTOK + kb + key0) * 32 + clogK * 8);
  const uint4* kg1 = (const uint4*)(K + (size_t)(h * NTOK + kb + key0 + 64) * 32 + clogK * 8);
  int eV = t >> 4, cpV = t & 15;
  int clogV = cpV ^ eV;
  const uint4* vg0 = (const uint4*)(VT + (size_t)(h * 32 + eV) * NTOK + kb + clogV * 8);
  const uint4* vg1 = (const uint4*)(VT + (size_t)(h * 32 + eV + 16) * NTOK + kb + clogV * 8);

  bf16x8 qf0 = *(const bf16x8*)(Q + (size_t)(h * NTOK + q0w + l15) * 32 + g * 8);
  bf16x8 qf1 = *(const bf16x8*)(Q + (size_t)(h * NTOK + q0w + 16 + l15) * 32 + g * 8);

  union { u16 s[8]; bf16x8 v; } one8;
  #pragma unroll
  for (int j = 0; j < 8; ++j) one8.s[j] = 0x3F80;
  bf16x8 ones = one8.v;

  f32x4 oc[2][2];
  for (int u = 0; u < 2; ++u) for (int eb = 0; eb < 2; ++eb) oc[u][eb] = (f32x4){0.f,0.f,0.f,0.f};
  f32x4 als0 = {0.f,0.f,0.f,0.f}, als1 = {0.f,0.f,0.f,0.f};

  int kf_base = l15 * 32 + ((g ^ (l15 & 3)) * 8);

  gld16(kg0, &Ksh[0][wb]);
  gld16(kg1, &Ksh[0][wb + 2048]);
  gld16(vg0, &Vsh[0][wb]);
  gld16(vg1, &Vsh[0][wb + 2048]);

  for (int kt = 0; kt < 10; ++kt){
    int cur = kt & 1, nxt = cur ^ 1;
    if (kt < 9){
      gld16(kg0 + (kt + 1) * 512, &Ksh[nxt][wb]);
      gld16(kg1 + (kt + 1) * 512, &Ksh[nxt][wb + 2048]);
      gld16(vg0 + (kt + 1) * 16,  &Vsh[nxt][wb]);
      gld16(vg1 + (kt + 1) * 16,  &Vsh[nxt][wb + 2048]);
      asm volatile("s_waitcnt vmcnt(4)" ::: "memory");   // own tile-kt loads landed
    } else {
      asm volatile("s_waitcnt vmcnt(0)" ::: "memory");
    }
    __builtin_amdgcn_sched_barrier(0);
    __builtin_amdgcn_s_barrier();        // A: all waves' tile-kt loads landed
    __builtin_amdgcn_sched_barrier(0);
    __builtin_amdgcn_s_setprio(1);       // T5: favor compute waves over stagers
    const u16* kB = &Ksh[cur][0];
    const u16* vB = &Vsh[cur][0];
    #pragma unroll
    for (int ks = 0; ks < 4; ++ks){
      f32x4 z = {0.f,0.f,0.f,0.f};
      bf16x8 kf0 = *(const bf16x8*)(kB + kf_base + ks * 1024);
      bf16x8 kf1 = *(const bf16x8*)(kB + kf_base + ks * 1024 + 512);
      f32x4 s0a = mfma16(kf0, qf0, z);
      f32x4 s1a = mfma16(kf1, qf0, z);
      f32x4 s0b = mfma16(kf0, qf1, z);
      f32x4 s1b = mfma16(kf1, qf1, z);
      int vf_off = l15 * 128 + (((ks * 4 + g) ^ l15) * 8);
      bf16x8 vf0 = *(const bf16x8*)(vB + vf_off);
      bf16x8 vf1 = *(const bf16x8*)(vB + vf_off + 2048);
      float pa0 = __builtin_amdgcn_exp2f(s0a[0]);
      float pa1 = __builtin_amdgcn_exp2f(s0a[1]);
      float pa2 = __builtin_amdgcn_exp2f(s0a[2]);
      float pa3 = __builtin_amdgcn_exp2f(s0a[3]);
      float pa4 = __builtin_amdgcn_exp2f(s1a[0]);
      float pa5 = __builtin_amdgcn_exp2f(s1a[1]);
      float pa6 = __builtin_amdgcn_exp2f(s1a[2]);
      float pa7 = __builtin_amdgcn_exp2f(s1a[3]);
      union { bf16x8 v; u32 wd[4]; } pua;
      pua.wd[0] = cvtpk(pa0, pa1); pua.wd[1] = cvtpk(pa2, pa3);
      pua.wd[2] = cvtpk(pa4, pa5); pua.wd[3] = cvtpk(pa6, pa7);
      float pb0 = __builtin_amdgcn_exp2f(s0b[0]);
      float pb1 = __builtin_amdgcn_exp2f(s0b[1]);
      float pb2 = __builtin_amdgcn_exp2f(s0b[2]);
      float pb3 = __builtin_amdgcn_exp2f(s0b[3]);
      float pb4 = __builtin_amdgcn_exp2f(s1b[0]);
      float pb5 = __builtin_amdgcn_exp2f(s1b[1]);
      float pb6 = __builtin_amdgcn_exp2f(s1b[2]);
      float pb7 = __builtin_amdgcn_exp2f(s1b[3]);
      union { bf16x8 v; u32 wd[4]; } pub;
      pub.wd[0] = cvtpk(pb0, pb1); pub.wd[1] = cvtpk(pb2, pb3);
      pub.wd[2] = cvtpk(pb4, pb5); pub.wd[3] = cvtpk(pb6, pb7);
      oc[0][0] = mfma16(pua.v, vf0, oc[0][0]);
      oc[0][1] = mfma16(pua.v, vf1, oc[0][1]);
      oc[1][0] = mfma16(pub.v, vf0, oc[1][0]);
      oc[1][1] = mfma16(pub.v, vf1, oc[1][1]);
      als0 = mfma16(pua.v, ones, als0);      // row-sums, k-reduced by MFMA
      als1 = mfma16(pub.v, ones, als1);
    }
    __builtin_amdgcn_s_setprio(0);
    __builtin_amdgcn_sched_barrier(0);
    __builtin_amdgcn_s_barrier();        // B: all waves done reading buf[cur]
  }

  // epilogue: Opb[h][n][sp][e], lpart[h][n][sp]
  u16* opp = Opb + (((size_t)h * NTOK + q0w) * 4 + sp) * 32;
  for (int u = 0; u < 2; ++u)
    for (int eb = 0; eb < 2; ++eb)
      for (int r = 0; r < 4; ++r)
        opp[(u * 16 + 4 * g + r) * 128 + eb * 16 + l15] = f2b(oc[u][eb][r]);
  if (l15 == 0){
    float* lp = lpart + ((size_t)h * NTOK + q0w) * 4 + sp;
    #pragma unroll
    for (int r = 0; r < 4; ++r){
      lp[(4 * g + r) * 4]      = als0[r];
      lp[(16 + 4 * g + r) * 4] = als1[r];
    }
  }
}

// ---------------- K2b: merge split-K partials -> O bf16 [n][256]. grid 640.
// Coalesced: 4 sp-reads are 64B apart; lpart read is one float4.
__global__ __launch_bounds__(256) void k_omerge(
    const u16* __restrict__ Opb, const float* __restrict__ lpart, u16* __restrict__ O)
{
  int gid = blockIdx.x * 256 + threadIdx.x;     // 163,840 = 5120*8*4
  int n = gid >> 5, r = gid & 31, h = r >> 2, eo = r & 3;
  const u16* ob = Opb + ((size_t)h * NTOK + n) * 128 + eo * 8;
  float acc[8] = {0.f,0.f,0.f,0.f,0.f,0.f,0.f,0.f};
  #pragma unroll
  for (int sp = 0; sp < 4; ++sp){
    union { bf16x8 v; u16 s[8]; } u;
    u.v = *(const bf16x8*)(ob + sp * 32);
    #pragma unroll
    for (int j = 0; j < 8; ++j) acc[j] += b2f(u.s[j]);
  }
  float4 lv = *(const float4*)(lpart + ((size_t)h * NTOK + n) * 4);
  float rl = 1.0f / (lv.x + lv.y + lv.z + lv.w);
  union { bf16x8 v; u32 wd[4]; } o;
  #pragma unroll
  for (int j = 0; j < 4; ++j) o.wd[j] = cvtpk(acc[2*j] * rl, acc[2*j+1] * rl);
  *(bf16x8*)(O + n * 256 + h * 32 + eo * 8) = o.v;
}

// ---------------- K3: Xn = O @ W_out + X (f32) + LN partials. grid 320 x 64.
__global__ __launch_bounds__(64) void k_xn(
    const u16* __restrict__ O, const u16* __restrict__ Wto,
    const u16* __restrict__ X, float* __restrict__ Xn, float* __restrict__ partials)
{
  int b = blockIdx.x, lane = threadIdx.x, l15 = lane & 15, g = lane >> 4;
  int n0 = b * 16;
  int n = n0 + l15;
  f32x4 acc[4];
  #pragma unroll
  for (int nb = 0; nb < 4; ++nb) acc[nb] = (f32x4){0.f,0.f,0.f,0.f};
  #pragma unroll
  for (int ks = 0; ks < 8; ++ks){
    bf16x8 av = *(const bf16x8*)(O + (size_t)n * 256 + ks * 32 + g * 8);
    #pragma unroll
    for (int nb = 0; nb < 4; ++nb){
      bf16x8 bb = *(const bf16x8*)(Wto + (nb * 16 + l15) * 256 + ks * 32 + g * 8);
      acc[nb] = mfma16(av, bb, acc[nb]);
    }
  }
  float s1 = 0.f, s2 = 0.f;
  #pragma unroll
  for (int nb = 0; nb < 4; ++nb){
    int d = nb * 16 + l15;
    #pragma unroll
    for (int r = 0; r < 4; ++r){
      int nn = n0 + g * 4 + r;
      float v = acc[nb][r] + b2f(X[nn * 64 + d]);
      Xn[nn * 64 + d] = v;
      s1 += v; s2 += v * v;
    }
  }
  for (int off = 1; off < 64; off <<= 1){
    s1 += __shfl_xor(s1, off);
    s2 += __shfl_xor(s2, off);
  }
  if (lane == 0){
    partials[b * 2]     = s1;
    partials[b * 2 + 1] = s2;
  }
}

// ---------------- K4: global LN stats (320 partials) + gamma/beta + conv2d -> f32
__global__ __launch_bounds__(256) void k_out(
    const float* __restrict__ Xn, const float* __restrict__ partials,
    const float* __restrict__ gamma, const float* __restrict__ beta,
    const u16* __restrict__ Wcb, const float* __restrict__ bc,
    float* __restrict__ out)
{
  __shared__ float redA[8];
  __shared__ float murs2[2];
  __shared__ __align__(16) float Xs[80 * 16];
  int bid = blockIdx.x, t = threadIdx.x, w = t >> 6, lane = t & 63;
  int hh = bid >> 2, wq = (bid & 3) * 16;
  float s1 = 0.f, s2 = 0.f;
  for (int i = t; i < 320; i += 256){
    s1 += partials[2 * i];
    s2 += partials[2 * i + 1];
  }
  for (int off = 1; off < 64; off <<= 1){ s1 += __shfl_xor(s1, off); s2 += __shfl_xor(s2, off); }
  if (lane == 0){ redA[w * 2] = s1; redA[w * 2 + 1] = s2; }
  __syncthreads();
  if (t == 0){
    float S1 = redA[0] + redA[2] + redA[4] + redA[6];
    float S2 = redA[1] + redA[3] + redA[5] + redA[7];
    const float inv = 1.0f / 327680.0f;
    float mu = S1 * inv;
    murs2[0] = mu;
    murs2[1] = rsqrtf(S2 * inv - mu * mu + 1e-5f);
  }
  __syncthreads();
  float mu = murs2[0], rs = murs2[1];
  for (int i = t; i < 1280; i += 256){
    int c = i >> 4, ww = wq + (i & 15);
    int idx = (c * 64 + hh) * 64 + ww;
    Xs[i] = (Xn[idx] - mu) * rs * gamma[idx] + beta[idx];
  }
  __syncthreads();
  int o = t;
  const u16* wr = Wcb + o * 80;
  f32x4 acc4[4];
  for (int k = 0; k < 4; ++k) acc4[k] = (f32x4){0.f,0.f,0.f,0.f};
  for (int c = 0; c < 80; ++c){
    float wt = b2f(wr[c]);
    for (int k = 0; k < 4; ++k)
      acc4[k] += (*(const f32x4*)&Xs[c * 16 + k * 4]) * wt;
  }
  float bb = bc[o];
  for (int k = 0; k < 4; ++k)
    for (int j = 0; j < 4; ++j)
      out[o * 4096 + hh * 64 + wq + k * 4 + j] = acc4[k][j] + bb;
}

extern "C" void kernel_launch(void* const* d_in, const int* in_sizes, int n_in,
                              void* d_out, int out_size, void* d_ws, size_t ws_size,
                              hipStream_t stream) {
  const float* cond1 = (const float*)d_in[0];
  const float* cond2 = (const float*)d_in[1];
  const float* W_emb = (const float*)d_in[2];
  const float* b_emb = (const float*)d_in[3];
  const float* W_c3  = (const float*)d_in[4];
  const float* b_c3  = (const float*)d_in[5];
  const float* pos   = (const float*)d_in[6];
  const float* WQ    = (const float*)d_in[7];
  const float* WK    = (const float*)d_in[8];
  const float* WV    = (const float*)d_in[9];
  const float* W_out = (const float*)d_in[10];
  const float* gamma = (const float*)d_in[11];
  const float* beta  = (const float*)d_in[12];
  const float* Wc    = (const float*)d_in[13];
  const float* bc    = (const float*)d_in[14];
  float* out = (float*)d_out;
  char* ws = (char*)d_ws;

  u16*   X   = (u16*)(ws);                    // 655,360
  u16*   Q   = (u16*)(ws +   655360);         // 2,621,440
  u16*   Kq  = (u16*)(ws +  3276800);         // 2,621,440
  u16*   VT  = (u16*)(ws +  5898240);         // 2,621,440
  u16*   O   = (u16*)(ws +  8519680);         // 5120*256*2 = 2,621,440
  float* Xn  = (float*)(ws + 11141120);       // 1,310,720
  u16*   Wt  = (u16*)(ws + 12451840);         // 98,304
  u16*   Wto = (u16*)(ws + 12550144);         // 32,768
  float* partials = (float*)(ws + 12582912);  // 2,560
  u16*   Wemb_b = (u16*)(ws + 12585472);      // 8,192
  u16*   Wc3_b  = (u16*)(ws + 12593664);      // 8,192
  u16*   Wcb    = (u16*)(ws + 12601856);      // 40,960
  u16*   Opb    = (u16*)(ws + 12648448);      // 8*5120*4*32*2 = 10,485,760
  float* lpart  = (float*)(ws + 23134208);    // 8*5120*4*4    = 655,360 (end 23,789,568)

  k_prep<<<32, 256, 0, stream>>>(WQ, WK, WV, W_out, W_emb, W_c3, Wc,
                                 Wt, Wto, Wemb_b, Wc3_b, Wcb);
  k_build_x<<<80, 256, 0, stream>>>(cond1, cond2, Wemb_b, b_emb, Wc3_b, b_c3, pos, X);
  k_qkv<<<480, 256, 0, stream>>>(X, Wt, Q, Kq, VT);
  k_attn<<<1280, 256, 0, stream>>>(Q, Kq, VT, Opb, lpart);
  k_omerge<<<640, 256, 0, stream>>>(Opb, lpart, O);
  k_xn<<<320, 64, 0, stream>>>(O, Wto, X, Xn, partials);
  k_out<<<256, 256, 0, stream>>>(Xn, partials, gamma, beta, Wcb, bc, out);
}

// Round 13
// 81.591 us; speedup vs baseline: 1.0355x; 1.0355x over previous
//
#include <hip/hip_runtime.h>
#include <hip/hip_bf16.h>

typedef short bf16x8 __attribute__((ext_vector_type(8)));
typedef float f32x4 __attribute__((ext_vector_type(4)));
typedef unsigned short u16;
typedef unsigned int u32;

#define NTOK 5120
#define NSDF 4096

__device__ __forceinline__ float b2f(u16 x){
  u32 u = ((u32)x) << 16; float f; __builtin_memcpy(&f, &u, 4); return f;
}
__device__ __forceinline__ u16 f2b(float f){
  u32 u; __builtin_memcpy(&u, &f, 4);
  return (u16)((u + 0x7fffu + ((u >> 16) & 1u)) >> 16);
}
__device__ __forceinline__ u32 cvtpk(float lo, float hi){
  u32 r;
  asm("v_cvt_pk_bf16_f32 %0, %1, %2" : "=v"(r) : "v"(lo), "v"(hi));
  return r;
}
__device__ __forceinline__ f32x4 mfma16(bf16x8 a, bf16x8 b, f32x4 c){
  return __builtin_amdgcn_mfma_f32_16x16x32_bf16(a, b, c, 0, 0, 0);
}
__device__ __forceinline__ void gld16(const void* g, void* l){
  __builtin_amdgcn_global_load_lds(
      (const __attribute__((address_space(1))) u32*)g,
      (__attribute__((address_space(3))) u32*)l, 16, 0, 0);
}

// ---------------- Kp: convert/transpose all weights f32 -> bf16 into ws
__global__ __launch_bounds__(256) void k_prep(
    const float* __restrict__ WQ, const float* __restrict__ WK, const float* __restrict__ WV,
    const float* __restrict__ W_out, const float* __restrict__ W_emb,
    const float* __restrict__ W_c3, const float* __restrict__ Wc,
    u16* __restrict__ Wt, u16* __restrict__ Wto, u16* __restrict__ Wemb_b,
    u16* __restrict__ Wc3_b, u16* __restrict__ Wcb)
{
  int gid = blockIdx.x * 256 + threadIdx.x;
  int gsz = gridDim.x * 256;
  for (int i = gid; i < 49152; i += gsz){       // 3*8*64*32
    int m = i >> 14, r = i & 16383;
    int h = r >> 11, d = (r >> 5) & 63, e = r & 31;
    const float* src = (m == 0) ? WQ : ((m == 1) ? WK : WV);
    float v = src[(h * 64 + d) * 32 + e];
    if (m == 0) v *= 0.17677669529663689f * 1.4426950408889634f;  // 1/sqrt(32)*log2(e)
    Wt[((m * 8 + h) * 32 + e) * 64 + d] = f2b(v);
  }
  for (int i = gid; i < 16384; i += gsz){       // 256*64
    int k = i >> 6, d = i & 63;
    Wto[d * 256 + k] = f2b(W_out[i]);
  }
  for (int i = gid; i < 4096; i += gsz) Wemb_b[i] = f2b(W_emb[i]);
  for (int i = gid; i < 4096; i += gsz) Wc3_b[i] = f2b(W_c3[i]);
  for (int i = gid; i < 20480; i += gsz) Wcb[i] = f2b(Wc[i]);
}

// ---------------- K0: patch embed (sdf + frames) + pos_emb -> X (bf16 [5120][64])
__global__ __launch_bounds__(256) void k_build_x(
    const float* __restrict__ cond1, const float* __restrict__ cond2,
    const u16* __restrict__ Wemb_b, const float* __restrict__ b_emb,
    const u16* __restrict__ Wc3_b, const float* __restrict__ b_c3,
    const float* __restrict__ pos, u16* __restrict__ Xout)
{
  __shared__ __align__(16) u16 Psh[64][72];
  int b = blockIdx.x, t = threadIdx.x;
  bool sdb = (b < 64);
  {
    int nl = t >> 2, sub = t & 3;
    const float* src = sdb ? cond1 : cond2;
    int nn = sdb ? (b * 64 + nl) : (b * 64 + nl - NSDF);
    int g0 = nn >> 8, g1 = (nn >> 4) & 15, g2 = nn & 15;
    const float* sp = src + (g0 * 4 + sub) * 4096 + g1 * 4 * 64 + g2 * 4;
    for (int p1 = 0; p1 < 4; ++p1){
      float4 v = *(const float4*)(sp + p1 * 64);
      ushort4 o;
      o.x = f2b(v.x); o.y = f2b(v.y); o.z = f2b(v.z); o.w = f2b(v.w);
      *(ushort4*)&Psh[nl][sub * 16 + p1 * 4] = o;
    }
  }
  __syncthreads();
  int w = t >> 6, lane = t & 63, l15 = lane & 15, g = lane >> 4;
  const u16* Wm = sdb ? Wc3_b : Wemb_b;
  const float* bias = sdb ? b_c3 : b_emb;
  bf16x8 a0 = *(const bf16x8*)&Psh[w * 16 + l15][g * 8];
  bf16x8 a1 = *(const bf16x8*)&Psh[w * 16 + l15][32 + g * 8];
  for (int nb = 0; nb < 4; ++nb){
    bf16x8 b0 = *(const bf16x8*)(Wm + (nb * 16 + l15) * 64 + g * 8);
    bf16x8 b1 = *(const bf16x8*)(Wm + (nb * 16 + l15) * 64 + 32 + g * 8);
    f32x4 acc = {0.f, 0.f, 0.f, 0.f};
    acc = mfma16(a0, b0, acc);
    acc = mfma16(a1, b1, acc);
    int d = nb * 16 + l15;
    float bs = bias[d];
    for (int r = 0; r < 4; ++r){
      int tok = b * 64 + w * 16 + g * 4 + r;
      float v = acc[r] + bs + pos[tok * 64 + d];
      Xout[tok * 64 + d] = f2b(v);
    }
  }
}

// ---------------- K1: QKV projection, wave-per-(m,h)-pair. grid 480 = 80 x 6.
__global__ __launch_bounds__(256) void k_qkv(
    const u16* __restrict__ X, const u16* __restrict__ Wt,
    u16* __restrict__ Q, u16* __restrict__ K, u16* __restrict__ VT)
{
  __shared__ __align__(16) u16 Xsh[64][72];
  int bid = blockIdx.x, b = bid / 6, grp = bid % 6;
  int t = threadIdx.x;
  {
    int nl = t >> 2, cb = t & 3;
    const u16* sp = X + (b * 64 + nl) * 64 + cb * 16;
    *(bf16x8*)&Xsh[nl][cb * 16] = *(const bf16x8*)(sp);
    *(bf16x8*)&Xsh[nl][cb * 16 + 8] = *(const bf16x8*)(sp + 8);
  }
  __syncthreads();
  int w = t >> 6, lane = t & 63, l15 = lane & 15, g = lane >> 4;
  int pair = grp * 4 + w, m = pair >> 3, h = pair & 7;
  bf16x8 a0[4], a1[4];
  for (int ms = 0; ms < 4; ++ms){
    a0[ms] = *(const bf16x8*)&Xsh[ms * 16 + l15][g * 8];
    a1[ms] = *(const bf16x8*)&Xsh[ms * 16 + l15][32 + g * 8];
  }
  for (int nb = 0; nb < 2; ++nb){
    const u16* wp = Wt + ((m * 8 + h) * 32 + nb * 16 + l15) * 64;
    bf16x8 b0 = *(const bf16x8*)(wp + g * 8);
    bf16x8 b1 = *(const bf16x8*)(wp + 32 + g * 8);
    int e = nb * 16 + l15;
    for (int ms = 0; ms < 4; ++ms){
      f32x4 acc = {0.f, 0.f, 0.f, 0.f};
      acc = mfma16(a0[ms], b0, acc);
      acc = mfma16(a1[ms], b1, acc);
      for (int r = 0; r < 4; ++r){
        int n = b * 64 + ms * 16 + g * 4 + r;
        u16 v = f2b(acc[r]);
        if (m == 0)      Q[(h * NTOK + n) * 32 + e] = v;
        else if (m == 1) K[(h * NTOK + n) * 32 + e] = v;
        else             VT[(h * 32 + e) * NTOK + n] = v;
      }
    }
  }
}

// ---------------- K2: flash attention, counted-vmcnt pipeline (r11-exact, 45.7us).
// split-K x4, XCD swizzle, 4 waves x 32q, 128-kv block-coop tiles, gld16 dbuf.
// Raw s_barriers + per-wave s_waitcnt vmcnt(4); ls row-sums via ones-MFMA.
__global__ __launch_bounds__(256) void k_attn(
    const u16* __restrict__ Q, const u16* __restrict__ K, const u16* __restrict__ VT,
    u16* __restrict__ Opb, float* __restrict__ lpart)
{
  __shared__ __align__(16) u16 Ksh[2][128 * 32];
  __shared__ __align__(16) u16 Vsh[2][32 * 128];
  int bid = blockIdx.x;
  int x = bid & 7;
  int inner = bid >> 3;
  int qb = inner % 40;
  int p = x + 8 * (inner / 40);
  int sp = p >> 3, h = p & 7;
  int t = threadIdx.x, w = t >> 6, lane = t & 63, l15 = lane & 15, g = lane >> 4;
  int q0w = qb * 128 + w * 32;
  int kb = sp * 1280;
  int wb = w * 512;

  int rho0 = t >> 2, cpK = t & 3;
  int key0 = (rho0 & 0x60) | ((rho0 & 0x0C) << 1) | ((rho0 & 0x10) >> 2) | (rho0 & 3);
  int clogK = cpK ^ (rho0 & 3);
  const uint4* kg0 = (const uint4*)(K + (size_t)(h * NTOK + kb + key0) * 32 + clogK * 8);
  const uint4* kg1 = (const uint4*)(K + (size_t)(h * NTOK + kb + key0 + 64) * 32 + clogK * 8);
  int eV = t >> 4, cpV = t & 15;
  int clogV = cpV ^ eV;
  const uint4* vg0 = (const uint4*)(VT + (size_t)(h * 32 + eV) * NTOK + kb + clogV * 8);
  const uint4* vg1 = (const uint4*)(VT + (size_t)(h * 32 + eV + 16) * NTOK + kb + clogV * 8);

  bf16x8 qf0 = *(const bf16x8*)(Q + (size_t)(h * NTOK + q0w + l15) * 32 + g * 8);
  bf16x8 qf1 = *(const bf16x8*)(Q + (size_t)(h * NTOK + q0w + 16 + l15) * 32 + g * 8);

  union { u16 s[8]; bf16x8 v; } one8;
  #pragma unroll
  for (int j = 0; j < 8; ++j) one8.s[j] = 0x3F80;
  bf16x8 ones = one8.v;

  f32x4 oc[2][2];
  for (int u = 0; u < 2; ++u) for (int eb = 0; eb < 2; ++eb) oc[u][eb] = (f32x4){0.f,0.f,0.f,0.f};
  f32x4 als0 = {0.f,0.f,0.f,0.f}, als1 = {0.f,0.f,0.f,0.f};

  int kf_base = l15 * 32 + ((g ^ (l15 & 3)) * 8);

  gld16(kg0, &Ksh[0][wb]);
  gld16(kg1, &Ksh[0][wb + 2048]);
  gld16(vg0, &Vsh[0][wb]);
  gld16(vg1, &Vsh[0][wb + 2048]);

  for (int kt = 0; kt < 10; ++kt){
    int cur = kt & 1, nxt = cur ^ 1;
    if (kt < 9){
      gld16(kg0 + (kt + 1) * 512, &Ksh[nxt][wb]);
      gld16(kg1 + (kt + 1) * 512, &Ksh[nxt][wb + 2048]);
      gld16(vg0 + (kt + 1) * 16,  &Vsh[nxt][wb]);
      gld16(vg1 + (kt + 1) * 16,  &Vsh[nxt][wb + 2048]);
      asm volatile("s_waitcnt vmcnt(4)" ::: "memory");   // own tile-kt loads landed
    } else {
      asm volatile("s_waitcnt vmcnt(0)" ::: "memory");
    }
    __builtin_amdgcn_sched_barrier(0);
    __builtin_amdgcn_s_barrier();        // A: all waves' tile-kt loads landed
    __builtin_amdgcn_sched_barrier(0);
    const u16* kB = &Ksh[cur][0];
    const u16* vB = &Vsh[cur][0];
    #pragma unroll
    for (int ks = 0; ks < 4; ++ks){
      f32x4 z = {0.f,0.f,0.f,0.f};
      bf16x8 kf0 = *(const bf16x8*)(kB + kf_base + ks * 1024);
      bf16x8 kf1 = *(const bf16x8*)(kB + kf_base + ks * 1024 + 512);
      f32x4 s0a = mfma16(kf0, qf0, z);
      f32x4 s1a = mfma16(kf1, qf0, z);
      f32x4 s0b = mfma16(kf0, qf1, z);
      f32x4 s1b = mfma16(kf1, qf1, z);
      int vf_off = l15 * 128 + (((ks * 4 + g) ^ l15) * 8);
      bf16x8 vf0 = *(const bf16x8*)(vB + vf_off);
      bf16x8 vf1 = *(const bf16x8*)(vB + vf_off + 2048);
      float pa0 = __builtin_amdgcn_exp2f(s0a[0]);
      float pa1 = __builtin_amdgcn_exp2f(s0a[1]);
      float pa2 = __builtin_amdgcn_exp2f(s0a[2]);
      float pa3 = __builtin_amdgcn_exp2f(s0a[3]);
      float pa4 = __builtin_amdgcn_exp2f(s1a[0]);
      float pa5 = __builtin_amdgcn_exp2f(s1a[1]);
      float pa6 = __builtin_amdgcn_exp2f(s1a[2]);
      float pa7 = __builtin_amdgcn_exp2f(s1a[3]);
      union { bf16x8 v; u32 wd[4]; } pua;
      pua.wd[0] = cvtpk(pa0, pa1); pua.wd[1] = cvtpk(pa2, pa3);
      pua.wd[2] = cvtpk(pa4, pa5); pua.wd[3] = cvtpk(pa6, pa7);
      float pb0 = __builtin_amdgcn_exp2f(s0b[0]);
      float pb1 = __builtin_amdgcn_exp2f(s0b[1]);
      float pb2 = __builtin_amdgcn_exp2f(s0b[2]);
      float pb3 = __builtin_amdgcn_exp2f(s0b[3]);
      float pb4 = __builtin_amdgcn_exp2f(s1b[0]);
      float pb5 = __builtin_amdgcn_exp2f(s1b[1]);
      float pb6 = __builtin_amdgcn_exp2f(s1b[2]);
      float pb7 = __builtin_amdgcn_exp2f(s1b[3]);
      union { bf16x8 v; u32 wd[4]; } pub;
      pub.wd[0] = cvtpk(pb0, pb1); pub.wd[1] = cvtpk(pb2, pb3);
      pub.wd[2] = cvtpk(pb4, pb5); pub.wd[3] = cvtpk(pb6, pb7);
      oc[0][0] = mfma16(pua.v, vf0, oc[0][0]);
      oc[0][1] = mfma16(pua.v, vf1, oc[0][1]);
      oc[1][0] = mfma16(pub.v, vf0, oc[1][0]);
      oc[1][1] = mfma16(pub.v, vf1, oc[1][1]);
      als0 = mfma16(pua.v, ones, als0);      // row-sums, k-reduced by MFMA
      als1 = mfma16(pub.v, ones, als1);
    }
    __builtin_amdgcn_sched_barrier(0);
    __builtin_amdgcn_s_barrier();        // B: all waves done reading buf[cur]
  }

  u16* opp = Opb + ((size_t)(sp * 8 + h) * NTOK + q0w) * 32;
  for (int u = 0; u < 2; ++u)
    for (int eb = 0; eb < 2; ++eb)
      for (int r = 0; r < 4; ++r)
        opp[(u * 16 + 4 * g + r) * 32 + eb * 16 + l15] = f2b(oc[u][eb][r]);
  if (l15 == 0){
    float* lp = lpart + (size_t)(sp * 8 + h) * NTOK + q0w;
    #pragma unroll
    for (int r = 0; r < 4; ++r){
      lp[4 * g + r]      = als0[r];
      lp[16 + 4 * g + r] = als1[r];
    }
  }
}

// ---------------- K3: fused split-K merge + Xn = O @ W_out + X + LN partials.
// grid 320 x 64 threads (r7-proven static version; all register indices static).
__global__ __launch_bounds__(64) void k_xn(
    const u16* __restrict__ Opb, const float* __restrict__ lpart,
    const u16* __restrict__ Wto, const u16* __restrict__ X,
    float* __restrict__ Xn, float* __restrict__ partials)
{
  int b = blockIdx.x, lane = threadIdx.x, l15 = lane & 15, g = lane >> 4;
  int n0 = b * 16;
  int n = n0 + l15;
  f32x4 acc[4];
  #pragma unroll
  for (int nb = 0; nb < 4; ++nb) acc[nb] = (f32x4){0.f,0.f,0.f,0.f};
  #pragma unroll
  for (int ks = 0; ks < 8; ++ks){               // ks == head
    float l = lpart[(size_t)(0 * 8 + ks) * NTOK + n]
            + lpart[(size_t)(1 * 8 + ks) * NTOK + n]
            + lpart[(size_t)(2 * 8 + ks) * NTOK + n]
            + lpart[(size_t)(3 * 8 + ks) * NTOK + n];
    float rl = 1.0f / l;
    float ac0 = 0.f, ac1 = 0.f, ac2 = 0.f, ac3 = 0.f;
    float ac4 = 0.f, ac5 = 0.f, ac6 = 0.f, ac7 = 0.f;
    #pragma unroll
    for (int sp = 0; sp < 4; ++sp){
      union { bf16x8 v; u16 s[8]; } u;
      u.v = *(const bf16x8*)(Opb + (((size_t)(sp * 8 + ks) * NTOK + n) << 5) + g * 8);
      ac0 += b2f(u.s[0]); ac1 += b2f(u.s[1]); ac2 += b2f(u.s[2]); ac3 += b2f(u.s[3]);
      ac4 += b2f(u.s[4]); ac5 += b2f(u.s[5]); ac6 += b2f(u.s[6]); ac7 += b2f(u.s[7]);
    }
    union { bf16x8 v; u32 wd[4]; } m;
    m.wd[0] = cvtpk(ac0 * rl, ac1 * rl);
    m.wd[1] = cvtpk(ac2 * rl, ac3 * rl);
    m.wd[2] = cvtpk(ac4 * rl, ac5 * rl);
    m.wd[3] = cvtpk(ac6 * rl, ac7 * rl);
    bf16x8 av = m.v;
    #pragma unroll
    for (int nb = 0; nb < 4; ++nb){
      bf16x8 bb = *(const bf16x8*)(Wto + (nb * 16 + l15) * 256 + ks * 32 + g * 8);
      acc[nb] = mfma16(av, bb, acc[nb]);
    }
  }
  float s1 = 0.f, s2 = 0.f;
  #pragma unroll
  for (int nb = 0; nb < 4; ++nb){
    int d = nb * 16 + l15;
    #pragma unroll
    for (int r = 0; r < 4; ++r){
      int nn = n0 + g * 4 + r;
      float v = acc[nb][r] + b2f(X[nn * 64 + d]);
      Xn[nn * 64 + d] = v;
      s1 += v; s2 += v * v;
    }
  }
  for (int off = 1; off < 64; off <<= 1){
    s1 += __shfl_xor(s1, off);
    s2 += __shfl_xor(s2, off);
  }
  if (lane == 0){
    partials[b * 2]     = s1;
    partials[b * 2 + 1] = s2;
  }
}

// ---------------- K4: global LN stats (320 partials) + gamma/beta + conv2d -> f32
__global__ __launch_bounds__(256) void k_out(
    const float* __restrict__ Xn, const float* __restrict__ partials,
    const float* __restrict__ gamma, const float* __restrict__ beta,
    const u16* __restrict__ Wcb, const float* __restrict__ bc,
    float* __restrict__ out)
{
  __shared__ float redA[8];
  __shared__ float murs2[2];
  __shared__ __align__(16) float Xs[80 * 16];
  int bid = blockIdx.x, t = threadIdx.x, w = t >> 6, lane = t & 63;
  int hh = bid >> 2, wq = (bid & 3) * 16;
  float s1 = 0.f, s2 = 0.f;
  for (int i = t; i < 320; i += 256){
    s1 += partials[2 * i];
    s2 += partials[2 * i + 1];
  }
  for (int off = 1; off < 64; off <<= 1){ s1 += __shfl_xor(s1, off); s2 += __shfl_xor(s2, off); }
  if (lane == 0){ redA[w * 2] = s1; redA[w * 2 + 1] = s2; }
  __syncthreads();
  if (t == 0){
    float S1 = redA[0] + redA[2] + redA[4] + redA[6];
    float S2 = redA[1] + redA[3] + redA[5] + redA[7];
    const float inv = 1.0f / 327680.0f;
    float mu = S1 * inv;
    murs2[0] = mu;
    murs2[1] = rsqrtf(S2 * inv - mu * mu + 1e-5f);
  }
  __syncthreads();
  float mu = murs2[0], rs = murs2[1];
  for (int i = t; i < 1280; i += 256){
    int c = i >> 4, ww = wq + (i & 15);
    int idx = (c * 64 + hh) * 64 + ww;
    Xs[i] = (Xn[idx] - mu) * rs * gamma[idx] + beta[idx];
  }
  __syncthreads();
  int o = t;
  const u16* wr = Wcb + o * 80;
  f32x4 acc4[4];
  for (int k = 0; k < 4; ++k) acc4[k] = (f32x4){0.f,0.f,0.f,0.f};
  for (int c = 0; c < 80; ++c){
    float wt = b2f(wr[c]);
    for (int k = 0; k < 4; ++k)
      acc4[k] += (*(const f32x4*)&Xs[c * 16 + k * 4]) * wt;
  }
  float bb = bc[o];
  for (int k = 0; k < 4; ++k)
    for (int j = 0; j < 4; ++j)
      out[o * 4096 + hh * 64 + wq + k * 4 + j] = acc4[k][j] + bb;
}

extern "C" void kernel_launch(void* const* d_in, const int* in_sizes, int n_in,
                              void* d_out, int out_size, void* d_ws, size_t ws_size,
                              hipStream_t stream) {
  const float* cond1 = (const float*)d_in[0];
  const float* cond2 = (const float*)d_in[1];
  const float* W_emb = (const float*)d_in[2];
  const float* b_emb = (const float*)d_in[3];
  const float* W_c3  = (const float*)d_in[4];
  const float* b_c3  = (const float*)d_in[5];
  const float* pos   = (const float*)d_in[6];
  const float* WQ    = (const float*)d_in[7];
  const float* WK    = (const float*)d_in[8];
  const float* WV    = (const float*)d_in[9];
  const float* W_out = (const float*)d_in[10];
  const float* gamma = (const float*)d_in[11];
  const float* beta  = (const float*)d_in[12];
  const float* Wc    = (const float*)d_in[13];
  const float* bc    = (const float*)d_in[14];
  float* out = (float*)d_out;
  char* ws = (char*)d_ws;

  u16*   X   = (u16*)(ws);                    // 655,360
  u16*   Q   = (u16*)(ws +   655360);         // 2,621,440
  u16*   Kq  = (u16*)(ws +  3276800);         // 2,621,440
  u16*   VT  = (u16*)(ws +  5898240);         // 2,621,440
  float* Xn  = (float*)(ws + 11141120);       // 1,310,720
  u16*   Wt  = (u16*)(ws + 12451840);         // 98,304
  u16*   Wto = (u16*)(ws + 12550144);         // 32,768
  float* partials = (float*)(ws + 12582912);  // 2,560
  u16*   Wemb_b = (u16*)(ws + 12585472);      // 8,192
  u16*   Wc3_b  = (u16*)(ws + 12593664);      // 8,192
  u16*   Wcb    = (u16*)(ws + 12601856);      // 40,960
  u16*   Opb    = (u16*)(ws + 12648448);      // 4*8*5120*32*2 = 10,485,760
  float* lpart  = (float*)(ws + 23134208);    // 4*8*5120*4    = 655,360 (end 23,789,568)

  k_prep<<<32, 256, 0, stream>>>(WQ, WK, WV, W_out, W_emb, W_c3, Wc,
                                 Wt, Wto, Wemb_b, Wc3_b, Wcb);
  k_build_x<<<80, 256, 0, stream>>>(cond1, cond2, Wemb_b, b_emb, Wc3_b, b_c3, pos, X);
  k_qkv<<<480, 256, 0, stream>>>(X, Wt, Q, Kq, VT);
  k_attn<<<1280, 256, 0, stream>>>(Q, Kq, VT, Opb, lpart);
  k_xn<<<320, 64, 0, stream>>>(Opb, lpart, Wto, X, Xn, partials);
  k_out<<<256, 256, 0, stream>>>(Xn, partials, gamma, beta, Wcb, bc, out);
}

// Round 14
// 73.765 us; speedup vs baseline: 1.1454x; 1.1061x over previous
//
#include <hip/hip_runtime.h>
#include <hip/hip_bf16.h>

typedef short bf16x8 __attribute__((ext_vector_type(8)));
typedef float f32x4 __attribute__((ext_vector_type(4)));
typedef unsigned short u16;
typedef unsigned int u32;

#define NTOK 5120
#define NSDF 4096

__device__ __forceinline__ float b2f(u16 x){
  u32 u = ((u32)x) << 16; float f; __builtin_memcpy(&f, &u, 4); return f;
}
__device__ __forceinline__ u16 f2b(float f){
  u32 u; __builtin_memcpy(&u, &f, 4);
  return (u16)((u + 0x7fffu + ((u >> 16) & 1u)) >> 16);
}
__device__ __forceinline__ u32 cvtpk(float lo, float hi){
  u32 r;
  asm("v_cvt_pk_bf16_f32 %0, %1, %2" : "=v"(r) : "v"(lo), "v"(hi));
  return r;
}
__device__ __forceinline__ f32x4 mfma16(bf16x8 a, bf16x8 b, f32x4 c){
  return __builtin_amdgcn_mfma_f32_16x16x32_bf16(a, b, c, 0, 0, 0);
}
__device__ __forceinline__ void gld16(const void* g, void* l){
  __builtin_amdgcn_global_load_lds(
      (const __attribute__((address_space(1))) u32*)g,
      (__attribute__((address_space(3))) u32*)l, 16, 0, 0);
}

// ---------------- K0: patch embed + pos_emb -> X; blocks 80..111 do weight prep.
// Blocks 0..79 are self-contained (convert own 64x64 patch weight into LDS).
__global__ __launch_bounds__(256) void k_build_x(
    const float* __restrict__ cond1, const float* __restrict__ cond2,
    const float* __restrict__ W_emb, const float* __restrict__ b_emb,
    const float* __restrict__ W_c3, const float* __restrict__ b_c3,
    const float* __restrict__ pos, u16* __restrict__ Xout,
    const float* __restrict__ WQ, const float* __restrict__ WK,
    const float* __restrict__ WV, const float* __restrict__ W_out,
    const float* __restrict__ Wc,
    u16* __restrict__ Wt, u16* __restrict__ Wto, u16* __restrict__ Wcb)
{
  __shared__ __align__(16) u16 Psh[64][72];
  __shared__ __align__(16) u16 Wsh[64][72];
  int b = blockIdx.x, t = threadIdx.x;
  if (b >= 80){
    // ---- prep blocks: convert Wt / Wto / Wcb (consumed by LATER kernels only)
    int gid = (b - 80) * 256 + t;
    const int gsz = 32 * 256;
    for (int i = gid; i < 49152; i += gsz){       // 3*8*64*32
      int m = i >> 14, r = i & 16383;
      int h = r >> 11, d = (r >> 5) & 63, e = r & 31;
      const float* src = (m == 0) ? WQ : ((m == 1) ? WK : WV);
      float v = src[(h * 64 + d) * 32 + e];
      if (m == 0) v *= 0.17677669529663689f * 1.4426950408889634f;  // 1/sqrt(32)*log2e
      Wt[((m * 8 + h) * 32 + e) * 64 + d] = f2b(v);
    }
    for (int i = gid; i < 16384; i += gsz){       // 256*64
      int k = i >> 6, d = i & 63;
      Wto[d * 256 + k] = f2b(W_out[i]);
    }
    for (int i = gid; i < 20480; i += gsz) Wcb[i] = f2b(Wc[i]);
    return;
  }
  bool sdb = (b < 64);
  {
    int nl = t >> 2, sub = t & 3;
    const float* src = sdb ? cond1 : cond2;
    int nn = sdb ? (b * 64 + nl) : (b * 64 + nl - NSDF);
    int g0 = nn >> 8, g1 = (nn >> 4) & 15, g2 = nn & 15;
    const float* sp = src + (g0 * 4 + sub) * 4096 + g1 * 4 * 64 + g2 * 4;
    for (int p1 = 0; p1 < 4; ++p1){
      float4 v = *(const float4*)(sp + p1 * 64);
      ushort4 o;
      o.x = f2b(v.x); o.y = f2b(v.y); o.z = f2b(v.z); o.w = f2b(v.w);
      *(ushort4*)&Psh[nl][sub * 16 + p1 * 4] = o;
    }
  }
  {
    const float* Wf = sdb ? W_c3 : W_emb;       // [64][64] row-major f32
    for (int i = t; i < 4096; i += 256)
      Wsh[i >> 6][i & 63] = f2b(Wf[i]);
  }
  __syncthreads();
  int w = t >> 6, lane = t & 63, l15 = lane & 15, g = lane >> 4;
  const float* bias = sdb ? b_c3 : b_emb;
  bf16x8 a0 = *(const bf16x8*)&Psh[w * 16 + l15][g * 8];
  bf16x8 a1 = *(const bf16x8*)&Psh[w * 16 + l15][32 + g * 8];
  for (int nb = 0; nb < 4; ++nb){
    bf16x8 b0 = *(const bf16x8*)&Wsh[nb * 16 + l15][g * 8];
    bf16x8 b1 = *(const bf16x8*)&Wsh[nb * 16 + l15][32 + g * 8];
    f32x4 acc = {0.f, 0.f, 0.f, 0.f};
    acc = mfma16(a0, b0, acc);
    acc = mfma16(a1, b1, acc);
    int d = nb * 16 + l15;
    float bs = bias[d];
    for (int r = 0; r < 4; ++r){
      int tok = b * 64 + w * 16 + g * 4 + r;
      float v = acc[r] + bs + pos[tok * 64 + d];
      Xout[tok * 64 + d] = f2b(v);
    }
  }
}

// ---------------- K1: QKV projection, wave-per-(m,h)-pair. grid 480 = 80 x 6.
// V (grp 4,5) routed through LDS transpose -> 128B-contiguous VT row writes.
__global__ __launch_bounds__(256) void k_qkv(
    const u16* __restrict__ X, const u16* __restrict__ Wt,
    u16* __restrict__ Q, u16* __restrict__ K, u16* __restrict__ VT)
{
  __shared__ __align__(16) u16 Xsh[64][72];
  __shared__ __align__(16) u16 Vsh[4][32][72];
  int bid = blockIdx.x, b = bid / 6, grp = bid % 6;
  int t = threadIdx.x;
  {
    int nl = t >> 2, cb = t & 3;
    const u16* sp = X + (b * 64 + nl) * 64 + cb * 16;
    *(bf16x8*)&Xsh[nl][cb * 16] = *(const bf16x8*)(sp);
    *(bf16x8*)&Xsh[nl][cb * 16 + 8] = *(const bf16x8*)(sp + 8);
  }
  __syncthreads();
  int w = t >> 6, lane = t & 63, l15 = lane & 15, g = lane >> 4;
  int pair = grp * 4 + w, m = pair >> 3, h = pair & 7;
  bf16x8 a0[4], a1[4];
  for (int ms = 0; ms < 4; ++ms){
    a0[ms] = *(const bf16x8*)&Xsh[ms * 16 + l15][g * 8];
    a1[ms] = *(const bf16x8*)&Xsh[ms * 16 + l15][32 + g * 8];
  }
  if (grp < 4){
    // m == 0 (Q) or 1 (K): coalesced row-major [h][n][e] writes
    for (int nb = 0; nb < 2; ++nb){
      const u16* wp = Wt + ((m * 8 + h) * 32 + nb * 16 + l15) * 64;
      bf16x8 b0 = *(const bf16x8*)(wp + g * 8);
      bf16x8 b1 = *(const bf16x8*)(wp + 32 + g * 8);
      int e = nb * 16 + l15;
      for (int ms = 0; ms < 4; ++ms){
        f32x4 acc = {0.f, 0.f, 0.f, 0.f};
        acc = mfma16(a0[ms], b0, acc);
        acc = mfma16(a1[ms], b1, acc);
        for (int r = 0; r < 4; ++r){
          int n = b * 64 + ms * 16 + g * 4 + r;
          u16 v = f2b(acc[r]);
          if (m == 0) Q[(h * NTOK + n) * 32 + e] = v;
          else        K[(h * NTOK + n) * 32 + e] = v;
        }
      }
    }
  } else {
    // m == 2 (V): stage [e][n] into LDS, then contiguous VT row writes
    for (int nb = 0; nb < 2; ++nb){
      const u16* wp = Wt + ((2 * 8 + h) * 32 + nb * 16 + l15) * 64;
      bf16x8 b0 = *(const bf16x8*)(wp + g * 8);
      bf16x8 b1 = *(const bf16x8*)(wp + 32 + g * 8);
      int e = nb * 16 + l15;
      for (int ms = 0; ms < 4; ++ms){
        f32x4 acc = {0.f, 0.f, 0.f, 0.f};
        acc = mfma16(a0[ms], b0, acc);
        acc = mfma16(a1[ms], b1, acc);
        for (int r = 0; r < 4; ++r)
          Vsh[w][e][ms * 16 + g * 4 + r] = f2b(acc[r]);
      }
    }
    __syncthreads();
    // 128 rows (hl,e) x 64 u16; lane-pairs cover one 128B row contiguously
    int hl = t >> 6, e = (t >> 1) & 31, part = t & 1;
    int hglob = (grp - 4) * 4 + hl;
    const u16* src = &Vsh[hl][e][part * 32];
    u16* dst = VT + (size_t)(hglob * 32 + e) * NTOK + b * 64 + part * 32;
    #pragma unroll
    for (int j = 0; j < 4; ++j)
      *(uint4*)(dst + j * 8) = *(const uint4*)(src + j * 8);
  }
}

// ---------------- K2: flash attention, counted-vmcnt pipeline (r11/r13-exact, 45.5us).
__global__ __launch_bounds__(256) void k_attn(
    const u16* __restrict__ Q, const u16* __restrict__ K, const u16* __restrict__ VT,
    u16* __restrict__ Opb, float* __restrict__ lpart)
{
  __shared__ __align__(16) u16 Ksh[2][128 * 32];
  __shared__ __align__(16) u16 Vsh[2][32 * 128];
  int bid = blockIdx.x;
  int x = bid & 7;
  int inner = bid >> 3;
  int qb = inner % 40;
  int p = x + 8 * (inner / 40);
  int sp = p >> 3, h = p & 7;
  int t = threadIdx.x, w = t >> 6, lane = t & 63, l15 = lane & 15, g = lane >> 4;
  int q0w = qb * 128 + w * 32;
  int kb = sp * 1280;
  int wb = w * 512;

  int rho0 = t >> 2, cpK = t & 3;
  int key0 = (rho0 & 0x60) | ((rho0 & 0x0C) << 1) | ((rho0 & 0x10) >> 2) | (rho0 & 3);
  int clogK = cpK ^ (rho0 & 3);
  const uint4* kg0 = (const uint4*)(K + (size_t)(h * NTOK + kb + key0) * 32 + clogK * 8);
  const uint4* kg1 = (const uint4*)(K + (size_t)(h * NTOK + kb + key0 + 64) * 32 + clogK * 8);
  int eV = t >> 4, cpV = t & 15;
  int clogV = cpV ^ eV;
  const uint4* vg0 = (const uint4*)(VT + (size_t)(h * 32 + eV) * NTOK + kb + clogV * 8);
  const uint4* vg1 = (const uint4*)(VT + (size_t)(h * 32 + eV + 16) * NTOK + kb + clogV * 8);

  bf16x8 qf0 = *(const bf16x8*)(Q + (size_t)(h * NTOK + q0w + l15) * 32 + g * 8);
  bf16x8 qf1 = *(const bf16x8*)(Q + (size_t)(h * NTOK + q0w + 16 + l15) * 32 + g * 8);

  union { u16 s[8]; bf16x8 v; } one8;
  #pragma unroll
  for (int j = 0; j < 8; ++j) one8.s[j] = 0x3F80;
  bf16x8 ones = one8.v;

  f32x4 oc[2][2];
  for (int u = 0; u < 2; ++u) for (int eb = 0; eb < 2; ++eb) oc[u][eb] = (f32x4){0.f,0.f,0.f,0.f};
  f32x4 als0 = {0.f,0.f,0.f,0.f}, als1 = {0.f,0.f,0.f,0.f};

  int kf_base = l15 * 32 + ((g ^ (l15 & 3)) * 8);

  gld16(kg0, &Ksh[0][wb]);
  gld16(kg1, &Ksh[0][wb + 2048]);
  gld16(vg0, &Vsh[0][wb]);
  gld16(vg1, &Vsh[0][wb + 2048]);

  for (int kt = 0; kt < 10; ++kt){
    int cur = kt & 1, nxt = cur ^ 1;
    if (kt < 9){
      gld16(kg0 + (kt + 1) * 512, &Ksh[nxt][wb]);
      gld16(kg1 + (kt + 1) * 512, &Ksh[nxt][wb + 2048]);
      gld16(vg0 + (kt + 1) * 16,  &Vsh[nxt][wb]);
      gld16(vg1 + (kt + 1) * 16,  &Vsh[nxt][wb + 2048]);
      asm volatile("s_waitcnt vmcnt(4)" ::: "memory");   // own tile-kt loads landed
    } else {
      asm volatile("s_waitcnt vmcnt(0)" ::: "memory");
    }
    __builtin_amdgcn_sched_barrier(0);
    __builtin_amdgcn_s_barrier();        // A: all waves' tile-kt loads landed
    __builtin_amdgcn_sched_barrier(0);
    const u16* kB = &Ksh[cur][0];
    const u16* vB = &Vsh[cur][0];
    #pragma unroll
    for (int ks = 0; ks < 4; ++ks){
      f32x4 z = {0.f,0.f,0.f,0.f};
      bf16x8 kf0 = *(const bf16x8*)(kB + kf_base + ks * 1024);
      bf16x8 kf1 = *(const bf16x8*)(kB + kf_base + ks * 1024 + 512);
      f32x4 s0a = mfma16(kf0, qf0, z);
      f32x4 s1a = mfma16(kf1, qf0, z);
      f32x4 s0b = mfma16(kf0, qf1, z);
      f32x4 s1b = mfma16(kf1, qf1, z);
      int vf_off = l15 * 128 + (((ks * 4 + g) ^ l15) * 8);
      bf16x8 vf0 = *(const bf16x8*)(vB + vf_off);
      bf16x8 vf1 = *(const bf16x8*)(vB + vf_off + 2048);
      float pa0 = __builtin_amdgcn_exp2f(s0a[0]);
      float pa1 = __builtin_amdgcn_exp2f(s0a[1]);
      float pa2 = __builtin_amdgcn_exp2f(s0a[2]);
      float pa3 = __builtin_amdgcn_exp2f(s0a[3]);
      float pa4 = __builtin_amdgcn_exp2f(s1a[0]);
      float pa5 = __builtin_amdgcn_exp2f(s1a[1]);
      float pa6 = __builtin_amdgcn_exp2f(s1a[2]);
      float pa7 = __builtin_amdgcn_exp2f(s1a[3]);
      union { bf16x8 v; u32 wd[4]; } pua;
      pua.wd[0] = cvtpk(pa0, pa1); pua.wd[1] = cvtpk(pa2, pa3);
      pua.wd[2] = cvtpk(pa4, pa5); pua.wd[3] = cvtpk(pa6, pa7);
      float pb0 = __builtin_amdgcn_exp2f(s0b[0]);
      float pb1 = __builtin_amdgcn_exp2f(s0b[1]);
      float pb2 = __builtin_amdgcn_exp2f(s0b[2]);
      float pb3 = __builtin_amdgcn_exp2f(s0b[3]);
      float pb4 = __builtin_amdgcn_exp2f(s1b[0]);
      float pb5 = __builtin_amdgcn_exp2f(s1b[1]);
      float pb6 = __builtin_amdgcn_exp2f(s1b[2]);
      float pb7 = __builtin_amdgcn_exp2f(s1b[3]);
      union { bf16x8 v; u32 wd[4]; } pub;
      pub.wd[0] = cvtpk(pb0, pb1); pub.wd[1] = cvtpk(pb2, pb3);
      pub.wd[2] = cvtpk(pb4, pb5); pub.wd[3] = cvtpk(pb6, pb7);
      oc[0][0] = mfma16(pua.v, vf0, oc[0][0]);
      oc[0][1] = mfma16(pua.v, vf1, oc[0][1]);
      oc[1][0] = mfma16(pub.v, vf0, oc[1][0]);
      oc[1][1] = mfma16(pub.v, vf1, oc[1][1]);
      als0 = mfma16(pua.v, ones, als0);      // row-sums, k-reduced by MFMA
      als1 = mfma16(pub.v, ones, als1);
    }
    __builtin_amdgcn_sched_barrier(0);
    __builtin_amdgcn_s_barrier();        // B: all waves done reading buf[cur]
  }

  u16* opp = Opb + ((size_t)(sp * 8 + h) * NTOK + q0w) * 32;
  for (int u = 0; u < 2; ++u)
    for (int eb = 0; eb < 2; ++eb)
      for (int r = 0; r < 4; ++r)
        opp[(u * 16 + 4 * g + r) * 32 + eb * 16 + l15] = f2b(oc[u][eb][r]);
  if (l15 == 0){
    float* lp = lpart + (size_t)(sp * 8 + h) * NTOK + q0w;
    #pragma unroll
    for (int r = 0; r < 4; ++r){
      lp[4 * g + r]      = als0[r];
      lp[16 + 4 * g + r] = als1[r];
    }
  }
}

// ---------------- K3: fused split-K merge + Xn = O @ W_out + X + LN partials.
__global__ __launch_bounds__(64) void k_xn(
    const u16* __restrict__ Opb, const float* __restrict__ lpart,
    const u16* __restrict__ Wto, const u16* __restrict__ X,
    float* __restrict__ Xn, float* __restrict__ partials)
{
  int b = blockIdx.x, lane = threadIdx.x, l15 = lane & 15, g = lane >> 4;
  int n0 = b * 16;
  int n = n0 + l15;
  f32x4 acc[4];
  #pragma unroll
  for (int nb = 0; nb < 4; ++nb) acc[nb] = (f32x4){0.f,0.f,0.f,0.f};
  #pragma unroll
  for (int ks = 0; ks < 8; ++ks){               // ks == head
    float l = lpart[(size_t)(0 * 8 + ks) * NTOK + n]
            + lpart[(size_t)(1 * 8 + ks) * NTOK + n]
            + lpart[(size_t)(2 * 8 + ks) * NTOK + n]
            + lpart[(size_t)(3 * 8 + ks) * NTOK + n];
    float rl = 1.0f / l;
    float ac0 = 0.f, ac1 = 0.f, ac2 = 0.f, ac3 = 0.f;
    float ac4 = 0.f, ac5 = 0.f, ac6 = 0.f, ac7 = 0.f;
    #pragma unroll
    for (int sp = 0; sp < 4; ++sp){
      union { bf16x8 v; u16 s[8]; } u;
      u.v = *(const bf16x8*)(Opb + (((size_t)(sp * 8 + ks) * NTOK + n) << 5) + g * 8);
      ac0 += b2f(u.s[0]); ac1 += b2f(u.s[1]); ac2 += b2f(u.s[2]); ac3 += b2f(u.s[3]);
      ac4 += b2f(u.s[4]); ac5 += b2f(u.s[5]); ac6 += b2f(u.s[6]); ac7 += b2f(u.s[7]);
    }
    union { bf16x8 v; u32 wd[4]; } m;
    m.wd[0] = cvtpk(ac0 * rl, ac1 * rl);
    m.wd[1] = cvtpk(ac2 * rl, ac3 * rl);
    m.wd[2] = cvtpk(ac4 * rl, ac5 * rl);
    m.wd[3] = cvtpk(ac6 * rl, ac7 * rl);
    bf16x8 av = m.v;
    #pragma unroll
    for (int nb = 0; nb < 4; ++nb){
      bf16x8 bb = *(const bf16x8*)(Wto + (nb * 16 + l15) * 256 + ks * 32 + g * 8);
      acc[nb] = mfma16(av, bb, acc[nb]);
    }
  }
  float s1 = 0.f, s2 = 0.f;
  #pragma unroll
  for (int nb = 0; nb < 4; ++nb){
    int d = nb * 16 + l15;
    #pragma unroll
    for (int r = 0; r < 4; ++r){
      int nn = n0 + g * 4 + r;
      float v = acc[nb][r] + b2f(X[nn * 64 + d]);
      Xn[nn * 64 + d] = v;
      s1 += v; s2 += v * v;
    }
  }
  for (int off = 1; off < 64; off <<= 1){
    s1 += __shfl_xor(s1, off);
    s2 += __shfl_xor(s2, off);
  }
  if (lane == 0){
    partials[b * 2]     = s1;
    partials[b * 2 + 1] = s2;
  }
}

// ---------------- K4: global LN stats (320 partials) + gamma/beta + conv2d -> f32
__global__ __launch_bounds__(256) void k_out(
    const float* __restrict__ Xn, const float* __restrict__ partials,
    const float* __restrict__ gamma, const float* __restrict__ beta,
    const u16* __restrict__ Wcb, const float* __restrict__ bc,
    float* __restrict__ out)
{
  __shared__ float redA[8];
  __shared__ float murs2[2];
  __shared__ __align__(16) float Xs[80 * 16];
  int bid = blockIdx.x, t = threadIdx.x, w = t >> 6, lane = t & 63;
  int hh = bid >> 2, wq = (bid & 3) * 16;
  float s1 = 0.f, s2 = 0.f;
  for (int i = t; i < 320; i += 256){
    s1 += partials[2 * i];
    s2 += partials[2 * i + 1];
  }
  for (int off = 1; off < 64; off <<= 1){ s1 += __shfl_xor(s1, off); s2 += __shfl_xor(s2, off); }
  if (lane == 0){ redA[w * 2] = s1; redA[w * 2 + 1] = s2; }
  __syncthreads();
  if (t == 0){
    float S1 = redA[0] + redA[2] + redA[4] + redA[6];
    float S2 = redA[1] + redA[3] + redA[5] + redA[7];
    const float inv = 1.0f / 327680.0f;
    float mu = S1 * inv;
    murs2[0] = mu;
    murs2[1] = rsqrtf(S2 * inv - mu * mu + 1e-5f);
  }
  __syncthreads();
  float mu = murs2[0], rs = murs2[1];
  for (int i = t; i < 1280; i += 256){
    int c = i >> 4, ww = wq + (i & 15);
    int idx = (c * 64 + hh) * 64 + ww;
    Xs[i] = (Xn[idx] - mu) * rs * gamma[idx] + beta[idx];
  }
  __syncthreads();
  int o = t;
  const u16* wr = Wcb + o * 80;
  f32x4 acc4[4];
  for (int k = 0; k < 4; ++k) acc4[k] = (f32x4){0.f,0.f,0.f,0.f};
  for (int c = 0; c < 80; ++c){
    float wt = b2f(wr[c]);
    for (int k = 0; k < 4; ++k)
      acc4[k] += (*(const f32x4*)&Xs[c * 16 + k * 4]) * wt;
  }
  float bb = bc[o];
  for (int k = 0; k < 4; ++k)
    for (int j = 0; j < 4; ++j)
      out[o * 4096 + hh * 64 + wq + k * 4 + j] = acc4[k][j] + bb;
}

extern "C" void kernel_launch(void* const* d_in, const int* in_sizes, int n_in,
                              void* d_out, int out_size, void* d_ws, size_t ws_size,
                              hipStream_t stream) {
  const float* cond1 = (const float*)d_in[0];
  const float* cond2 = (const float*)d_in[1];
  const float* W_emb = (const float*)d_in[2];
  const float* b_emb = (const float*)d_in[3];
  const float* W_c3  = (const float*)d_in[4];
  const float* b_c3  = (const float*)d_in[5];
  const float* pos   = (const float*)d_in[6];
  const float* WQ    = (const float*)d_in[7];
  const float* WK    = (const float*)d_in[8];
  const float* WV    = (const float*)d_in[9];
  const float* W_out = (const float*)d_in[10];
  const float* gamma = (const float*)d_in[11];
  const float* beta  = (const float*)d_in[12];
  const float* Wc    = (const float*)d_in[13];
  const float* bc    = (const float*)d_in[14];
  float* out = (float*)d_out;
  char* ws = (char*)d_ws;

  u16*   X   = (u16*)(ws);                    // 655,360
  u16*   Q   = (u16*)(ws +   655360);         // 2,621,440
  u16*   Kq  = (u16*)(ws +  3276800);         // 2,621,440
  u16*   VT  = (u16*)(ws +  5898240);         // 2,621,440
  float* Xn  = (float*)(ws + 11141120);       // 1,310,720
  u16*   Wt  = (u16*)(ws + 12451840);         // 98,304
  u16*   Wto = (u16*)(ws + 12550144);         // 32,768
  float* partials = (float*)(ws + 12582912);  // 2,560
  u16*   Wcb    = (u16*)(ws + 12601856);      // 40,960
  u16*   Opb    = (u16*)(ws + 12648448);      // 4*8*5120*32*2 = 10,485,760
  float* lpart  = (float*)(ws + 23134208);    // 4*8*5120*4    = 655,360 (end 23,789,568)

  k_build_x<<<112, 256, 0, stream>>>(cond1, cond2, W_emb, b_emb, W_c3, b_c3, pos, X,
                                     WQ, WK, WV, W_out, Wc, Wt, Wto, Wcb);
  k_qkv<<<480, 256, 0, stream>>>(X, Wt, Q, Kq, VT);
  k_attn<<<1280, 256, 0, stream>>>(Q, Kq, VT, Opb, lpart);
  k_xn<<<320, 64, 0, stream>>>(Opb, lpart, Wto, X, Xn, partials);
  k_out<<<256, 256, 0, stream>>>(Xn, partials, gamma, beta, Wcb, bc, out);
}

// Round 15
// 73.018 us; speedup vs baseline: 1.1571x; 1.0102x over previous
//
#include <hip/hip_runtime.h>
#include <hip/hip_bf16.h>

typedef short bf16x8 __attribute__((ext_vector_type(8)));
typedef float f32x4 __attribute__((ext_vector_type(4)));
typedef unsigned short u16;
typedef unsigned int u32;

#define NTOK 5120
#define NSDF 4096

__device__ __forceinline__ float b2f(u16 x){
  u32 u = ((u32)x) << 16; float f; __builtin_memcpy(&f, &u, 4); return f;
}
__device__ __forceinline__ u16 f2b(float f){
  u32 u; __builtin_memcpy(&u, &f, 4);
  return (u16)((u + 0x7fffu + ((u >> 16) & 1u)) >> 16);
}
__device__ __forceinline__ u32 cvtpk(float lo, float hi){
  u32 r;
  asm("v_cvt_pk_bf16_f32 %0, %1, %2" : "=v"(r) : "v"(lo), "v"(hi));
  return r;
}
__device__ __forceinline__ f32x4 mfma16(bf16x8 a, bf16x8 b, f32x4 c){
  return __builtin_amdgcn_mfma_f32_16x16x32_bf16(a, b, c, 0, 0, 0);
}
__device__ __forceinline__ void gld16(const void* g, void* l){
  __builtin_amdgcn_global_load_lds(
      (const __attribute__((address_space(1))) u32*)g,
      (__attribute__((address_space(3))) u32*)l, 16, 0, 0);
}

// ---------------- K1: fused embed + QKV. grid 480 = 80 b x 6 grp.
// Phase 0: stage patches; load pair QKV weights into register B-fragments (f32 src).
// Phase 1: embed MFMA (B-fragments direct from f32 weights) -> X (LDS + grp0 global).
// Phase 2: QKV projection; V routed through LDS transpose (r14-proven).
__global__ __launch_bounds__(256) void k_qkv(
    const float* __restrict__ cond1, const float* __restrict__ cond2,
    const float* __restrict__ W_emb, const float* __restrict__ b_emb,
    const float* __restrict__ W_c3, const float* __restrict__ b_c3,
    const float* __restrict__ pos,
    const float* __restrict__ WQ, const float* __restrict__ WK,
    const float* __restrict__ WV,
    u16* __restrict__ Xout, u16* __restrict__ Q, u16* __restrict__ K,
    u16* __restrict__ VT)
{
  __shared__ __align__(16) u16 Psh[64][72];
  __shared__ __align__(16) u16 Vsh[4][32][72];
  int bid = blockIdx.x, b = bid / 6, grp = bid % 6;
  int t = threadIdx.x, w = t >> 6, lane = t & 63, l15 = lane & 15, g = lane >> 4;
  bool sdb = (b < 64);

  // phase 0: stage patches into Psh (f32 -> bf16)
  {
    int nl = t >> 2, sub = t & 3;
    const float* src = sdb ? cond1 : cond2;
    int nn = sdb ? (b * 64 + nl) : (b * 64 + nl - NSDF);
    int g0 = nn >> 8, g1 = (nn >> 4) & 15, g2 = nn & 15;
    const float* sp = src + (g0 * 4 + sub) * 4096 + g1 * 4 * 64 + g2 * 4;
    for (int p1 = 0; p1 < 4; ++p1){
      float4 v = *(const float4*)(sp + p1 * 64);
      ushort4 o;
      o.x = f2b(v.x); o.y = f2b(v.y); o.z = f2b(v.z); o.w = f2b(v.w);
      *(ushort4*)&Psh[nl][sub * 16 + p1 * 4] = o;
    }
  }
  // per-wave QKV pair weights -> register B-fragments (scale folded for m==0)
  int pair = grp * 4 + w, m = pair >> 3, h = pair & 7;
  const float* wsrc = ((m == 0) ? WQ : ((m == 1) ? WK : WV)) + h * 64 * 32;
  float wscale = (m == 0) ? 0.17677669529663689f * 1.4426950408889634f : 1.0f;
  bf16x8 wb0[2], wb1[2];
  #pragma unroll
  for (int nb = 0; nb < 2; ++nb){
    union { bf16x8 v; u16 s[8]; } u0, u1;
    #pragma unroll
    for (int j = 0; j < 8; ++j){
      u0.s[j] = f2b(wsrc[(g * 8 + j) * 32 + nb * 16 + l15] * wscale);
      u1.s[j] = f2b(wsrc[(32 + g * 8 + j) * 32 + nb * 16 + l15] * wscale);
    }
    wb0[nb] = u0.v;
    wb1[nb] = u1.v;
  }
  __syncthreads();                       // patches staged

  // phase 1: embed (A from Psh, B direct from f32 weight rows)
  const float* Wf = sdb ? W_c3 : W_emb;  // [64][64] row-major
  const float* bias = sdb ? b_c3 : b_emb;
  bf16x8 pa0 = *(const bf16x8*)&Psh[w * 16 + l15][g * 8];
  bf16x8 pa1 = *(const bf16x8*)&Psh[w * 16 + l15][32 + g * 8];
  u16 xv[4][4];
  #pragma unroll
  for (int nb = 0; nb < 4; ++nb){
    union { bf16x8 v; u16 s[8]; } e0, e1;
    const float* wr = Wf + (nb * 16 + l15) * 64;
    #pragma unroll
    for (int j = 0; j < 8; ++j){
      e0.s[j] = f2b(wr[g * 8 + j]);
      e1.s[j] = f2b(wr[32 + g * 8 + j]);
    }
    f32x4 acc = {0.f, 0.f, 0.f, 0.f};
    acc = mfma16(pa0, e0.v, acc);
    acc = mfma16(pa1, e1.v, acc);
    int d = nb * 16 + l15;
    float bs = bias[d];
    #pragma unroll
    for (int r = 0; r < 4; ++r){
      int tok = b * 64 + w * 16 + g * 4 + r;
      u16 xb = f2b(acc[r] + bs + pos[tok * 64 + d]);
      xv[nb][r] = xb;
      if (grp == 0) Xout[tok * 64 + d] = xb;
    }
  }
  __syncthreads();                       // all pa loads done; safe to overwrite Psh
  #pragma unroll
  for (int nb = 0; nb < 4; ++nb)
    #pragma unroll
    for (int r = 0; r < 4; ++r)
      Psh[w * 16 + g * 4 + r][nb * 16 + l15] = xv[nb][r];
  __syncthreads();                       // X ready in Psh

  // phase 2: QKV
  bf16x8 a0[4], a1[4];
  #pragma unroll
  for (int ms = 0; ms < 4; ++ms){
    a0[ms] = *(const bf16x8*)&Psh[ms * 16 + l15][g * 8];
    a1[ms] = *(const bf16x8*)&Psh[ms * 16 + l15][32 + g * 8];
  }
  if (grp < 4){
    // m == 0 (Q) or 1 (K): coalesced row-major [h][n][e] writes
    #pragma unroll
    for (int nb = 0; nb < 2; ++nb){
      int e = nb * 16 + l15;
      #pragma unroll
      for (int ms = 0; ms < 4; ++ms){
        f32x4 acc = {0.f, 0.f, 0.f, 0.f};
        acc = mfma16(a0[ms], wb0[nb], acc);
        acc = mfma16(a1[ms], wb1[nb], acc);
        #pragma unroll
        for (int r = 0; r < 4; ++r){
          int n = b * 64 + ms * 16 + g * 4 + r;
          u16 v = f2b(acc[r]);
          if (m == 0) Q[(h * NTOK + n) * 32 + e] = v;
          else        K[(h * NTOK + n) * 32 + e] = v;
        }
      }
    }
  } else {
    // m == 2 (V): stage [e][n] into LDS, then contiguous VT row writes
    #pragma unroll
    for (int nb = 0; nb < 2; ++nb){
      int e = nb * 16 + l15;
      #pragma unroll
      for (int ms = 0; ms < 4; ++ms){
        f32x4 acc = {0.f, 0.f, 0.f, 0.f};
        acc = mfma16(a0[ms], wb0[nb], acc);
        acc = mfma16(a1[ms], wb1[nb], acc);
        #pragma unroll
        for (int r = 0; r < 4; ++r)
          Vsh[w][e][ms * 16 + g * 4 + r] = f2b(acc[r]);
      }
    }
    __syncthreads();
    int hl = t >> 6, e = (t >> 1) & 31, part = t & 1;
    int hglob = (grp - 4) * 4 + hl;
    const u16* src = &Vsh[hl][e][part * 32];
    u16* dst = VT + (size_t)(hglob * 32 + e) * NTOK + b * 64 + part * 32;
    #pragma unroll
    for (int j = 0; j < 4; ++j)
      *(uint4*)(dst + j * 8) = *(const uint4*)(src + j * 8);
  }
}

// ---------------- K2: flash attention (r13-exact compute, 45.5us) + 8 prep blocks.
// Blocks >= 1280 convert Wto/Wcb (consumed by LATER kernels) and exit.
__global__ __launch_bounds__(256) void k_attn(
    const u16* __restrict__ Q, const u16* __restrict__ K, const u16* __restrict__ VT,
    u16* __restrict__ Opb, float* __restrict__ lpart,
    const float* __restrict__ W_out, const float* __restrict__ Wc,
    u16* __restrict__ Wto, u16* __restrict__ Wcb)
{
  __shared__ __align__(16) u16 Ksh[2][128 * 32];
  __shared__ __align__(16) u16 Vsh[2][32 * 128];
  int bid = blockIdx.x;
  int t = threadIdx.x;
  if (bid >= 1280){
    int gid = (bid - 1280) * 256 + t;     // 0..2047
    for (int i = gid; i < 16384; i += 2048){
      int k2 = i >> 6, d = i & 63;
      Wto[d * 256 + k2] = f2b(W_out[i]);
    }
    for (int i = gid; i < 20480; i += 2048) Wcb[i] = f2b(Wc[i]);
    return;
  }
  int x = bid & 7;
  int inner = bid >> 3;
  int qb = inner % 40;
  int p = x + 8 * (inner / 40);
  int sp = p >> 3, h = p & 7;
  int w = t >> 6, lane = t & 63, l15 = lane & 15, g = lane >> 4;
  int q0w = qb * 128 + w * 32;
  int kb = sp * 1280;
  int wb = w * 512;

  int rho0 = t >> 2, cpK = t & 3;
  int key0 = (rho0 & 0x60) | ((rho0 & 0x0C) << 1) | ((rho0 & 0x10) >> 2) | (rho0 & 3);
  int clogK = cpK ^ (rho0 & 3);
  const uint4* kg0 = (const uint4*)(K + (size_t)(h * NTOK + kb + key0) * 32 + clogK * 8);
  const uint4* kg1 = (const uint4*)(K + (size_t)(h * NTOK + kb + key0 + 64) * 32 + clogK * 8);
  int eV = t >> 4, cpV = t & 15;
  int clogV = cpV ^ eV;
  const uint4* vg0 = (const uint4*)(VT + (size_t)(h * 32 + eV) * NTOK + kb + clogV * 8);
  const uint4* vg1 = (const uint4*)(VT + (size_t)(h * 32 + eV + 16) * NTOK + kb + clogV * 8);

  bf16x8 qf0 = *(const bf16x8*)(Q + (size_t)(h * NTOK + q0w + l15) * 32 + g * 8);
  bf16x8 qf1 = *(const bf16x8*)(Q + (size_t)(h * NTOK + q0w + 16 + l15) * 32 + g * 8);

  union { u16 s[8]; bf16x8 v; } one8;
  #pragma unroll
  for (int j = 0; j < 8; ++j) one8.s[j] = 0x3F80;
  bf16x8 ones = one8.v;

  f32x4 oc[2][2];
  for (int u = 0; u < 2; ++u) for (int eb = 0; eb < 2; ++eb) oc[u][eb] = (f32x4){0.f,0.f,0.f,0.f};
  f32x4 als0 = {0.f,0.f,0.f,0.f}, als1 = {0.f,0.f,0.f,0.f};

  int kf_base = l15 * 32 + ((g ^ (l15 & 3)) * 8);

  gld16(kg0, &Ksh[0][wb]);
  gld16(kg1, &Ksh[0][wb + 2048]);
  gld16(vg0, &Vsh[0][wb]);
  gld16(vg1, &Vsh[0][wb + 2048]);

  for (int kt = 0; kt < 10; ++kt){
    int cur = kt & 1, nxt = cur ^ 1;
    if (kt < 9){
      gld16(kg0 + (kt + 1) * 512, &Ksh[nxt][wb]);
      gld16(kg1 + (kt + 1) * 512, &Ksh[nxt][wb + 2048]);
      gld16(vg0 + (kt + 1) * 16,  &Vsh[nxt][wb]);
      gld16(vg1 + (kt + 1) * 16,  &Vsh[nxt][wb + 2048]);
      asm volatile("s_waitcnt vmcnt(4)" ::: "memory");   // own tile-kt loads landed
    } else {
      asm volatile("s_waitcnt vmcnt(0)" ::: "memory");
    }
    __builtin_amdgcn_sched_barrier(0);
    __builtin_amdgcn_s_barrier();        // A: all waves' tile-kt loads landed
    __builtin_amdgcn_sched_barrier(0);
    const u16* kB = &Ksh[cur][0];
    const u16* vB = &Vsh[cur][0];
    #pragma unroll
    for (int ks = 0; ks < 4; ++ks){
      f32x4 z = {0.f,0.f,0.f,0.f};
      bf16x8 kf0 = *(const bf16x8*)(kB + kf_base + ks * 1024);
      bf16x8 kf1 = *(const bf16x8*)(kB + kf_base + ks * 1024 + 512);
      f32x4 s0a = mfma16(kf0, qf0, z);
      f32x4 s1a = mfma16(kf1, qf0, z);
      f32x4 s0b = mfma16(kf0, qf1, z);
      f32x4 s1b = mfma16(kf1, qf1, z);
      int vf_off = l15 * 128 + (((ks * 4 + g) ^ l15) * 8);
      bf16x8 vf0 = *(const bf16x8*)(vB + vf_off);
      bf16x8 vf1 = *(const bf16x8*)(vB + vf_off + 2048);
      float pa0 = __builtin_amdgcn_exp2f(s0a[0]);
      float pa1 = __builtin_amdgcn_exp2f(s0a[1]);
      float pa2 = __builtin_amdgcn_exp2f(s0a[2]);
      float pa3 = __builtin_amdgcn_exp2f(s0a[3]);
      float pa4 = __builtin_amdgcn_exp2f(s1a[0]);
      float pa5 = __builtin_amdgcn_exp2f(s1a[1]);
      float pa6 = __builtin_amdgcn_exp2f(s1a[2]);
      float pa7 = __builtin_amdgcn_exp2f(s1a[3]);
      union { bf16x8 v; u32 wd[4]; } pua;
      pua.wd[0] = cvtpk(pa0, pa1); pua.wd[1] = cvtpk(pa2, pa3);
      pua.wd[2] = cvtpk(pa4, pa5); pua.wd[3] = cvtpk(pa6, pa7);
      float pb0 = __builtin_amdgcn_exp2f(s0b[0]);
      float pb1 = __builtin_amdgcn_exp2f(s0b[1]);
      float pb2 = __builtin_amdgcn_exp2f(s0b[2]);
      float pb3 = __builtin_amdgcn_exp2f(s0b[3]);
      float pb4 = __builtin_amdgcn_exp2f(s1b[0]);
      float pb5 = __builtin_amdgcn_exp2f(s1b[1]);
      float pb6 = __builtin_amdgcn_exp2f(s1b[2]);
      float pb7 = __builtin_amdgcn_exp2f(s1b[3]);
      union { bf16x8 v; u32 wd[4]; } pub;
      pub.wd[0] = cvtpk(pb0, pb1); pub.wd[1] = cvtpk(pb2, pb3);
      pub.wd[2] = cvtpk(pb4, pb5); pub.wd[3] = cvtpk(pb6, pb7);
      oc[0][0] = mfma16(pua.v, vf0, oc[0][0]);
      oc[0][1] = mfma16(pua.v, vf1, oc[0][1]);
      oc[1][0] = mfma16(pub.v, vf0, oc[1][0]);
      oc[1][1] = mfma16(pub.v, vf1, oc[1][1]);
      als0 = mfma16(pua.v, ones, als0);      // row-sums, k-reduced by MFMA
      als1 = mfma16(pub.v, ones, als1);
    }
    __builtin_amdgcn_sched_barrier(0);
    __builtin_amdgcn_s_barrier();        // B: all waves done reading buf[cur]
  }

  u16* opp = Opb + ((size_t)(sp * 8 + h) * NTOK + q0w) * 32;
  for (int u = 0; u < 2; ++u)
    for (int eb = 0; eb < 2; ++eb)
      for (int r = 0; r < 4; ++r)
        opp[(u * 16 + 4 * g + r) * 32 + eb * 16 + l15] = f2b(oc[u][eb][r]);
  if (l15 == 0){
    float* lp = lpart + (size_t)(sp * 8 + h) * NTOK + q0w;
    #pragma unroll
    for (int r = 0; r < 4; ++r){
      lp[4 * g + r]      = als0[r];
      lp[16 + 4 * g + r] = als1[r];
    }
  }
}

// ---------------- K3: fused split-K merge + Xn = O @ W_out + X + LN partials.
__global__ __launch_bounds__(64) void k_xn(
    const u16* __restrict__ Opb, const float* __restrict__ lpart,
    const u16* __restrict__ Wto, const u16* __restrict__ X,
    float* __restrict__ Xn, float* __restrict__ partials)
{
  int b = blockIdx.x, lane = threadIdx.x, l15 = lane & 15, g = lane >> 4;
  int n0 = b * 16;
  int n = n0 + l15;
  f32x4 acc[4];
  #pragma unroll
  for (int nb = 0; nb < 4; ++nb) acc[nb] = (f32x4){0.f,0.f,0.f,0.f};
  #pragma unroll
  for (int ks = 0; ks < 8; ++ks){               // ks == head
    float l = lpart[(size_t)(0 * 8 + ks) * NTOK + n]
            + lpart[(size_t)(1 * 8 + ks) * NTOK + n]
            + lpart[(size_t)(2 * 8 + ks) * NTOK + n]
            + lpart[(size_t)(3 * 8 + ks) * NTOK + n];
    float rl = 1.0f / l;
    float ac0 = 0.f, ac1 = 0.f, ac2 = 0.f, ac3 = 0.f;
    float ac4 = 0.f, ac5 = 0.f, ac6 = 0.f, ac7 = 0.f;
    #pragma unroll
    for (int sp = 0; sp < 4; ++sp){
      union { bf16x8 v; u16 s[8]; } u;
      u.v = *(const bf16x8*)(Opb + (((size_t)(sp * 8 + ks) * NTOK + n) << 5) + g * 8);
      ac0 += b2f(u.s[0]); ac1 += b2f(u.s[1]); ac2 += b2f(u.s[2]); ac3 += b2f(u.s[3]);
      ac4 += b2f(u.s[4]); ac5 += b2f(u.s[5]); ac6 += b2f(u.s[6]); ac7 += b2f(u.s[7]);
    }
    union { bf16x8 v; u32 wd[4]; } mm;
    mm.wd[0] = cvtpk(ac0 * rl, ac1 * rl);
    mm.wd[1] = cvtpk(ac2 * rl, ac3 * rl);
    mm.wd[2] = cvtpk(ac4 * rl, ac5 * rl);
    mm.wd[3] = cvtpk(ac6 * rl, ac7 * rl);
    bf16x8 av = mm.v;
    #pragma unroll
    for (int nb = 0; nb < 4; ++nb){
      bf16x8 bb = *(const bf16x8*)(Wto + (nb * 16 + l15) * 256 + ks * 32 + g * 8);
      acc[nb] = mfma16(av, bb, acc[nb]);
    }
  }
  float s1 = 0.f, s2 = 0.f;
  #pragma unroll
  for (int nb = 0; nb < 4; ++nb){
    int d = nb * 16 + l15;
    #pragma unroll
    for (int r = 0; r < 4; ++r){
      int nn = n0 + g * 4 + r;
      float v = acc[nb][r] + b2f(X[nn * 64 + d]);
      Xn[nn * 64 + d] = v;
      s1 += v; s2 += v * v;
    }
  }
  for (int off = 1; off < 64; off <<= 1){
    s1 += __shfl_xor(s1, off);
    s2 += __shfl_xor(s2, off);
  }
  if (lane == 0){
    partials[b * 2]     = s1;
    partials[b * 2 + 1] = s2;
  }
}

// ---------------- K4: global LN stats (320 partials) + gamma/beta + conv2d -> f32
__global__ __launch_bounds__(256) void k_out(
    const float* __restrict__ Xn, const float* __restrict__ partials,
    const float* __restrict__ gamma, const float* __restrict__ beta,
    const u16* __restrict__ Wcb, const float* __restrict__ bc,
    float* __restrict__ out)
{
  __shared__ float redA[8];
  __shared__ float murs2[2];
  __shared__ __align__(16) float Xs[80 * 16];
  int bid = blockIdx.x, t = threadIdx.x, w = t >> 6, lane = t & 63;
  int hh = bid >> 2, wq = (bid & 3) * 16;
  float s1 = 0.f, s2 = 0.f;
  for (int i = t; i < 320; i += 256){
    s1 += partials[2 * i];
    s2 += partials[2 * i + 1];
  }
  for (int off = 1; off < 64; off <<= 1){ s1 += __shfl_xor(s1, off); s2 += __shfl_xor(s2, off); }
  if (lane == 0){ redA[w * 2] = s1; redA[w * 2 + 1] = s2; }
  __syncthreads();
  if (t == 0){
    float S1 = redA[0] + redA[2] + redA[4] + redA[6];
    float S2 = redA[1] + redA[3] + redA[5] + redA[7];
    const float inv = 1.0f / 327680.0f;
    float mu = S1 * inv;
    murs2[0] = mu;
    murs2[1] = rsqrtf(S2 * inv - mu * mu + 1e-5f);
  }
  __syncthreads();
  float mu = murs2[0], rs = murs2[1];
  for (int i = t; i < 1280; i += 256){
    int c = i >> 4, ww = wq + (i & 15);
    int idx = (c * 64 + hh) * 64 + ww;
    Xs[i] = (Xn[idx] - mu) * rs * gamma[idx] + beta[idx];
  }
  __syncthreads();
  int o = t;
  const u16* wr = Wcb + o * 80;
  f32x4 acc4[4];
  for (int k = 0; k < 4; ++k) acc4[k] = (f32x4){0.f,0.f,0.f,0.f};
  for (int c = 0; c < 80; ++c){
    float wt = b2f(wr[c]);
    for (int k = 0; k < 4; ++k)
      acc4[k] += (*(const f32x4*)&Xs[c * 16 + k * 4]) * wt;
  }
  float bb = bc[o];
  for (int k = 0; k < 4; ++k)
    for (int j = 0; j < 4; ++j)
      out[o * 4096 + hh * 64 + wq + k * 4 + j] = acc4[k][j] + bb;
}

extern "C" void kernel_launch(void* const* d_in, const int* in_sizes, int n_in,
                              void* d_out, int out_size, void* d_ws, size_t ws_size,
                              hipStream_t stream) {
  const float* cond1 = (const float*)d_in[0];
  const float* cond2 = (const float*)d_in[1];
  const float* W_emb = (const float*)d_in[2];
  const float* b_emb = (const float*)d_in[3];
  const float* W_c3  = (const float*)d_in[4];
  const float* b_c3  = (const float*)d_in[5];
  const float* pos   = (const float*)d_in[6];
  const float* WQ    = (const float*)d_in[7];
  const float* WK    = (const float*)d_in[8];
  const float* WV    = (const float*)d_in[9];
  const float* W_out = (const float*)d_in[10];
  const float* gamma = (const float*)d_in[11];
  const float* beta  = (const float*)d_in[12];
  const float* Wc    = (const float*)d_in[13];
  const float* bc    = (const float*)d_in[14];
  float* out = (float*)d_out;
  char* ws = (char*)d_ws;

  u16*   X   = (u16*)(ws);                    // 655,360
  u16*   Q   = (u16*)(ws +   655360);         // 2,621,440
  u16*   Kq  = (u16*)(ws +  3276800);         // 2,621,440
  u16*   VT  = (u16*)(ws +  5898240);         // 2,621,440
  float* Xn  = (float*)(ws + 11141120);       // 1,310,720
  u16*   Wto = (u16*)(ws + 12550144);         // 32,768
  float* partials = (float*)(ws + 12582912);  // 2,560
  u16*   Wcb    = (u16*)(ws + 12601856);      // 40,960
  u16*   Opb    = (u16*)(ws + 12648448);      // 4*8*5120*32*2 = 10,485,760
  float* lpart  = (float*)(ws + 23134208);    // 4*8*5120*4    = 655,360 (end 23,789,568)

  k_qkv<<<480, 256, 0, stream>>>(cond1, cond2, W_emb, b_emb, W_c3, b_c3, pos,
                                 WQ, WK, WV, X, Q, Kq, VT);
  k_attn<<<1288, 256, 0, stream>>>(Q, Kq, VT, Opb, lpart, W_out, Wc, Wto, Wcb);
  k_xn<<<320, 64, 0, stream>>>(Opb, lpart, Wto, X, Xn, partials);
  k_out<<<256, 256, 0, stream>>>(Xn, partials, gamma, beta, Wcb, bc, out);
}